// Round 7
// baseline (368.041 us; speedup 1.0000x reference)
//
#include <hip/hip_runtime.h>
#include <hip/hip_bf16.h>

typedef __attribute__((ext_vector_type(8))) short short8v;
typedef __attribute__((ext_vector_type(4))) float floatx4;

#define LROW 130   // dwords per LDS tile row: 128 cols + 2 pad (2-way-free reads, 8B aligned)

__device__ __forceinline__ unsigned int pkbf(float a, float b) {
  __hip_bfloat162 h = __float22bfloat162_rn(make_float2(a, b));
  union { __hip_bfloat162 h; unsigned int u; } c; c.h = h;
  return c.u;
}

__device__ __forceinline__ void glds4(const float* g, float* l) {
  __builtin_amdgcn_global_load_lds(
      (const __attribute__((address_space(1))) void*)g,
      (__attribute__((address_space(3))) void*)l, 4, 0, 0);
}

// out[b*128+o] = bias[o]
__global__ void bias_init(const float* __restrict__ bias, float* __restrict__ out) {
  int idx = blockIdx.x * 256 + threadIdx.x;   // 32768 total
  out[idx] = bias[idx & 127];
}

// out[256,128] += F[256,Kc] @ W[Kc,128];  F[b,gk]=a[b,i]*p[b,j]*d[b,k], gk=(i*64+j)*64+k
// block c: i=c>>2, j in [(c&3)*16,+16), k in [0,64).
// W path: global_load_lds size=4 stages 32x128 fp32 tiles (dense 256B bursts, every
// line requested once per CU) into double-buffered LDS; fragments read 2-way-free.
__global__ __launch_bounds__(512, 2)
void tfn_gemm(const float* __restrict__ X, const float* __restrict__ P,
              const float* __restrict__ Dyn, const float* __restrict__ W,
              float* __restrict__ out) {
  __shared__ float Wl[2][32 * LROW];          // 2 x 16.25 KB W-tiles
  __shared__ float p_lds[16][256];            // p[jj][brow]

  const int tid = threadIdx.x;
  const int wv = tid >> 6, lane = tid & 63;
  const int q = lane >> 4, l16 = lane & 15;
  const int r = wv & 3;                       // rows [64r, 64r+64)
  const int cg = wv >> 2;                     // cols [64cg, 64cg+64)

  const int c = blockIdx.x;
  const int i = c >> 2;
  const int j0 = (c & 3) << 4;
  const long gk0 = (long)c << 10;

  for (int idx = tid; idx < 256 * 16; idx += 512) {
    int bb = idx >> 4, jj = idx & 15;
    int j = j0 + jj;
    p_lds[jj][bb] = (j < 63) ? P[bb * 63 + j] : 1.0f;
  }

  // e[rt][h][t] = a * d  (indices compile-time everywhere in the loop)
  float e[4][2][8];
  #pragma unroll
  for (int rt = 0; rt < 4; ++rt) {
    int brow = (r << 6) + (rt << 4) + l16;
    float av = (i < 63) ? X[brow * 63 + i] : 1.0f;
    #pragma unroll
    for (int h = 0; h < 2; ++h) {
      int kb = (h << 5) + (q << 3);
      #pragma unroll
      for (int t = 0; t < 8; ++t) {
        int k = kb + t;
        float dv = (k < 63) ? Dyn[brow * 63 + k] : 1.0f;
        e[rt][h][t] = av * dv;
      }
    }
  }

  floatx4 acc[4][4];
  #pragma unroll
  for (int a = 0; a < 4; ++a)
    #pragma unroll
    for (int b = 0; b < 4; ++b) acc[a][b] = (floatx4)0.0f;

  // stage tile s: wave wv handles in-tile rows [wv*4, wv*4+4), two 64-col halves
#define STAGE(sN, buf)                                                          \
  {                                                                             \
    const long krow = gk0 + ((long)(sN) << 5) + (wv << 2);                      \
    _Pragma("unroll") for (int rr = 0; rr < 4; ++rr)                            \
        _Pragma("unroll") for (int h2 = 0; h2 < 2; ++h2)                        \
            glds4(W + (krow + rr) * 128 + (h2 << 6) + lane,                     \
                  &Wl[buf][((wv << 2) + rr) * LROW + (h2 << 6)]);               \
  }

  STAGE(0, 0)
  __syncthreads();   // covers p_lds writes + tile 0

  const int foff = ((q << 3) * LROW) + (cg << 6) + l16;   // fragment base in tile

#define HALFSTEP(jj, h)                                                         \
  {                                                                             \
    const int s = ((jj) << 1) | (h);                                            \
    if (s < 31) STAGE(s + 1, 1 - (h))                                           \
    float wf[4][8];                                                             \
    const float* fr = &Wl[h][foff];                                             \
    _Pragma("unroll") for (int nt = 0; nt < 4; ++nt)                            \
        _Pragma("unroll") for (int t = 0; t < 8; ++t)                           \
            wf[nt][t] = fr[t * LROW + nt * 16];                                 \
    union { short8v v; unsigned int u[4]; } fb[4], fa[4];                       \
    _Pragma("unroll") for (int nt = 0; nt < 4; ++nt)                            \
        _Pragma("unroll") for (int v2 = 0; v2 < 4; ++v2)                        \
            fb[nt].u[v2] = pkbf(wf[nt][2 * v2], wf[nt][2 * v2 + 1]);            \
    _Pragma("unroll") for (int rt = 0; rt < 4; ++rt)                            \
        _Pragma("unroll") for (int v2 = 0; v2 < 4; ++v2)                        \
            fa[rt].u[v2] = pkbf(pb[rt] * e[rt][h][2 * v2],                      \
                                pb[rt] * e[rt][h][2 * v2 + 1]);                 \
    _Pragma("unroll") for (int rt = 0; rt < 4; ++rt)                            \
        _Pragma("unroll") for (int nt = 0; nt < 4; ++nt)                        \
            acc[rt][nt] = __builtin_amdgcn_mfma_f32_16x16x32_bf16(              \
                fa[rt].v, fb[nt].v, acc[rt][nt], 0, 0, 0);                      \
    __syncthreads();                                                            \
  }

  for (int jj = 0; jj < 16; ++jj) {
    float pb[4];
    #pragma unroll
    for (int rt = 0; rt < 4; ++rt)
      pb[rt] = p_lds[jj][(r << 6) + (rt << 4) + l16];
    HALFSTEP(jj, 0)   // tile in buf 0 (s even), prefetch odd tile into buf 1
    HALFSTEP(jj, 1)   // tile in buf 1 (s odd),  prefetch even tile into buf 0
  }
#undef HALFSTEP
#undef STAGE

  // epilogue: atomic accumulate, iteration order rotated by block to stagger contention
  #pragma unroll
  for (int rt0 = 0; rt0 < 4; ++rt0) {
    #pragma unroll
    for (int nt0 = 0; nt0 < 4; ++nt0) {
      const int rt = (rt0 + (c >> 2)) & 3;
      const int nt = (nt0 + c) & 3;
      int col = (cg << 6) + (nt << 4) + l16;
      #pragma unroll
      for (int g = 0; g < 4; ++g) {
        int brow = (r << 6) + (rt << 4) + (q << 2) + g;
        atomicAdd(&out[brow * 128 + col], acc[rt][nt][g]);
      }
    }
  }
}

extern "C" void kernel_launch(void* const* d_in, const int* in_sizes, int n_in,
                              void* d_out, int out_size, void* d_ws, size_t ws_size,
                              hipStream_t stream) {
  const float* x   = (const float*)d_in[0];
  const float* p   = (const float*)d_in[1];
  const float* dyn = (const float*)d_in[2];
  const float* W   = (const float*)d_in[3];
  const float* b   = (const float*)d_in[4];
  float* out = (float*)d_out;

  bias_init<<<128, 256, 0, stream>>>(b, out);
  tfn_gemm<<<256, 512, 0, stream>>>(x, p, dyn, W, out);
}